// Round 6
// baseline (2891.684 us; speedup 1.0000x reference)
//
#include <hip/hip_runtime.h>

// ---------------------------------------------------------------------------
// Model: x:(256,1,96) -> 24-layer biLSTM (scan over batch axis: N=96 rows are
// independent chains, T=256 steps) -> slice n in [48,96) -> 24-layer biLSTM
// (N=48) -> z=h2+x1 -> fc1(1536->1000,relu) -> fc2(1000->48) -> FP32 out.
//
// Round-6: FUSE all 48 LSTM layer-stages into ONE kernel. Chain n is a pure
// batch dim through both stacks; per layer the only cross-block dependency is
// the direction partner (d,n)<->(1-d,n). 192 persistent blocks (blockIdx=
// 2n+d, partners adjacent -> co-dispatched; 192 blocks x 64KB LDS all
// co-resident on 256 CUs). Per layer: xg compute in LDS (consumed-row reuse,
// exactly 64 KB), wave-0 scan (round-5 inner loop, unchanged arithmetic),
// 16KB h-panel exchange via global + device-scope release/acquire flag
// (monotone counter; canonical __syncthreads + threadfence + atomic pattern).
// Removes 48 launches, 48 pipeline drains, 48 cold x re-stagings.
// ---------------------------------------------------------------------------

template <int SEL>
__device__ __forceinline__ float quad_bcast(float v) {
  return __int_as_float(__builtin_amdgcn_update_dpp(
      0, __float_as_int(v), SEL * 0x55, 0xF, 0xF, true));
}

// hb:   [par2][d2][96][256][16]  rotating exchange buffers
// x1b:  [d2][48][256][16]        stack1 final h (n>=48), fc1's x1
// h2b:  [d2][48][256][16]        stack2 final h, fc1's h2
// flags:[192]                    monotone per-block layer counters
__global__ __launch_bounds__(256) void lstm_fused(
    const float* __restrict__ x, const float* __restrict__ W_ih0_1,
    const float* __restrict__ W_ih_1, const float* __restrict__ W_hh_1,
    const float* __restrict__ b_ih_1, const float* __restrict__ b_hh_1,
    const float* __restrict__ W_ih_2, const float* __restrict__ W_hh_2,
    const float* __restrict__ b_ih_2, const float* __restrict__ b_hh_2,
    float* __restrict__ hb, float* __restrict__ x1b, float* __restrict__ h2b,
    int* __restrict__ flags) {
  __shared__ float xg[256 * 64];  // rows: gates [0..64); x/h tail in [32..64)

  const int tid = threadIdx.x;
  const int lane = tid & 63;
  const int w = tid >> 6;
  const int bid = blockIdx.x;
  const int n = bid >> 1;
  const int d = bid & 1;
  const int pid = bid ^ 1;  // direction partner
  const int d16 = d * 16;
  const int jj = lane >> 2, g = lane & 3;

  const int nlay = (n < 48) ? 24 : 48;

  for (int L = 0; L < nlay; ++L) {
    const bool s2 = (L >= 24);
    const int l = s2 ? (L - 24) : L;

    // ---- partner wait + load partner h(L-1) into cols [32+(1-d)*16 ..) ----
    if (L > 0) {
      if (tid == 0) {
        while (__hip_atomic_load(&flags[pid], __ATOMIC_ACQUIRE,
                                 __HIP_MEMORY_SCOPE_AGENT) < L)
          __builtin_amdgcn_s_sleep(2);
      }
      __syncthreads();
      const float* src =
          (L == 24)
              ? (x1b + (((size_t)(1 - d) * 48 + (n - 48)) * 256) * 16)
              : (hb + ((((size_t)((L - 1) & 1) * 2 + (1 - d)) * 96 + n) * 256) *
                          16);
      const int c = (tid & 3) * 4;
#pragma unroll
      for (int p = 0; p < 4; ++p) {
        const int tt = (tid >> 2) + p * 64;
        const float4 v =
            *reinterpret_cast<const float4*>(src + (size_t)tt * 16 + c);
        *reinterpret_cast<float4*>(&xg[tt * 64 + 32 + (1 - d) * 16 + c]) = v;
      }
      __syncthreads();
    }

    // ---- per-lane weights for this (L, d) ----
    const int rL = lane;  // xg-compute gate row
    const float* bih = s2 ? b_ih_2 : b_ih_1;
    const float* bhh = s2 ? b_hh_2 : b_hh_1;
    const float bias = bih[l * 128 + d * 64 + rL] + bhh[l * 128 + d * 64 + rL];
    float wih[32];
    float wih0 = 0.f;
    if (L == 0) {
      wih0 = W_ih0_1[d * 64 + rL];
    } else {
      const float* Wih = s2 ? (W_ih_2 + (size_t)l * 4096)
                            : (W_ih_1 + (size_t)(l - 1) * 4096);
      const float4* wp =
          reinterpret_cast<const float4*>(Wih + ((size_t)d * 64 + rL) * 32);
#pragma unroll
      for (int q = 0; q < 8; ++q) {
        const float4 t4 = wp[q];
        wih[4 * q + 0] = t4.x;
        wih[4 * q + 1] = t4.y;
        wih[4 * q + 2] = t4.z;
        wih[4 * q + 3] = t4.w;
      }
    }

    // ---- xg compute: wave w handles rows [w*64, w*64+64) ----
    if (L == 0) {
      const float xv = x[(size_t)tid * 96 + n];  // one-time, small
      xg[tid * 64 + 32] = xv;
      __syncthreads();
      for (int ti = 0; ti < 64; ++ti) {
        const int t = w * 64 + ti;
        const float xs = xg[t * 64 + 32];  // read precedes write (same wave)
        xg[t * 64 + rL] = fmaf(wih0, xs, bias);
      }
    } else {
      for (int ti = 0; ti < 64; ++ti) {
        const int t = w * 64 + ti;
        const float4* xr = reinterpret_cast<const float4*>(&xg[t * 64 + 32]);
        float a0 = bias, a1 = 0.f, a2 = 0.f, a3 = 0.f;
#pragma unroll
        for (int q = 0; q < 8; ++q) {
          const float4 xv4 = xr[q];
          a0 = fmaf(wih[4 * q + 0], xv4.x, a0);
          a1 = fmaf(wih[4 * q + 1], xv4.y, a1);
          a2 = fmaf(wih[4 * q + 2], xv4.z, a2);
          a3 = fmaf(wih[4 * q + 3], xv4.w, a3);
        }
        xg[t * 64 + rL] = (a0 + a1) + (a2 + a3);
      }
    }
    __syncthreads();

    // ---- scan (wave 0 only); writes own h into row tails [32+d16..) ----
    if (w == 0) {
      const int r = g * 16 + jj;
      const float* Whh =
          s2 ? (W_hh_2 + (size_t)l * 2048) : (W_hh_1 + (size_t)l * 2048);
      float whh[16];
#pragma unroll
      for (int k = 0; k < 16; ++k) whh[k] = Whh[((size_t)d * 64 + r) * 16 + k];
      const float s_ = (g == 2) ? 2.885390082f : -1.442695041f;
      const float m_ = (g == 2) ? -2.0f : 1.0f;
      const float b_ = (g == 2) ? 1.0f : 0.0f;
      float hs[16];
#pragma unroll
      for (int k = 0; k < 16; ++k) hs[k] = 0.f;
      float c = 0.f;
      const int dt = d ? -1 : 1;
      int t = d ? 255 : 0;
      float cur0 = xg[t * 64 + r];
      float cur1 = xg[(t + dt) * 64 + r];

#define LSTM_STEP(CUR, TT)                                                \
  {                                                                       \
    float a0 = (CUR), a1 = 0.f, a2 = 0.f, a3 = 0.f;                       \
    _Pragma("unroll") for (int k = 0; k < 16; k += 4) {                   \
      a0 = fmaf(whh[k + 0], hs[k + 0], a0);                               \
      a1 = fmaf(whh[k + 1], hs[k + 1], a1);                               \
      a2 = fmaf(whh[k + 2], hs[k + 2], a2);                               \
      a3 = fmaf(whh[k + 3], hs[k + 3], a3);                               \
    }                                                                     \
    const float gv = (a0 + a1) + (a2 + a3);                               \
    const float e = __builtin_amdgcn_exp2f(s_ * gv);                      \
    const float v = fmaf(m_, __builtin_amdgcn_rcpf(1.0f + e), b_);        \
    const float si = quad_bcast<0>(v);                                    \
    const float sf = quad_bcast<1>(v);                                    \
    const float tg = quad_bcast<2>(v);                                    \
    const float so = quad_bcast<3>(v);                                    \
    c = fmaf(sf, c, si * tg);                                             \
    const float e2 = __builtin_amdgcn_exp2f(2.885390082f * c);            \
    const float th = fmaf(-2.0f, __builtin_amdgcn_rcpf(1.0f + e2), 1.0f); \
    const float h = so * th;                                              \
    if (g == 0) xg[(TT)*64 + 32 + d16 + jj] = h;                          \
    const int hbb = __float_as_int(h);                                    \
    _Pragma("unroll") for (int k = 0; k < 16; ++k) hs[k] =                \
        __int_as_float(__builtin_amdgcn_readlane(hbb, 4 * k));            \
  }

      for (int tt = 0; tt < 256; tt += 2) {
        const float nx0 = xg[((t + 2 * dt) & 255) * 64 + r];
        LSTM_STEP(cur0, t)
        const float nx1 = xg[((t + 3 * dt) & 255) * 64 + r];
        LSTM_STEP(cur1, t + dt)
        cur0 = nx0;
        cur1 = nx1;
        t += 2 * dt;
      }
#undef LSTM_STEP
    }
    __syncthreads();

    // ---- store own h panel (256 x 16 floats, coalesced float4) ----
    float* dst;
    if (L == 47)
      dst = h2b + (((size_t)d * 48 + (n - 48)) * 256) * 16;
    else if (L == 23 && n >= 48)
      dst = x1b + (((size_t)d * 48 + (n - 48)) * 256) * 16;
    else
      dst = hb + ((((size_t)(L & 1) * 2 + d) * 96 + n) * 256) * 16;
    {
      const int c = (tid & 3) * 4;
#pragma unroll
      for (int p = 0; p < 4; ++p) {
        const int tt = (tid >> 2) + p * 64;
        const float4 v =
            *reinterpret_cast<const float4*>(&xg[tt * 64 + 32 + d16 + c]);
        *reinterpret_cast<float4*>(dst + (size_t)tt * 16 + c) = v;
      }
    }
    __syncthreads();
    if (tid == 0) {
      __threadfence();  // make panel visible at agent scope before release
      __hip_atomic_store(&flags[bid], L + 1, __ATOMIC_RELEASE,
                         __HIP_MEMORY_SCOPE_AGENT);
    }
  }
}

// fc1: y1[b,m] = relu( sum_k (h2[b,k] + x1[b,k]) * w1[m,k] + b1[m] )
// h2/x1 layout: [d][n2][b][16]; k = n2*32 + d*16 + j.
__global__ __launch_bounds__(256) void fc1_kernel(
    const float* __restrict__ h2, const float* __restrict__ x1,
    const float* __restrict__ w1, const float* __restrict__ b1,
    float* __restrict__ y1) {
  __shared__ float Zs[16][68];
  __shared__ float Ws[16][68];
  const int tid = threadIdx.x;
  const int m0 = blockIdx.x * 64;
  const int b0 = blockIdx.y * 64;
  const int rr = tid >> 2;
  const int c4 = (tid & 3) * 4;
  const int tx = tid & 15, ty = tid >> 4;

  float acc[4][4];
#pragma unroll
  for (int i = 0; i < 4; ++i)
#pragma unroll
    for (int jj = 0; jj < 4; ++jj) acc[i][jj] = 0.f;

  const bool wvalid = (m0 + rr) < 1000;
  const float* wr = w1 + (size_t)(m0 + rr) * 1536 + c4;

  for (int k0 = 0; k0 < 1536; k0 += 16) {
    const int k = k0 + c4;
    const int n2 = k >> 5, dd = (k >> 4) & 1, j0 = k & 15;
    const size_t off = (((size_t)dd * 48 + n2) * 256 + (b0 + rr)) * 16 + j0;
    const float4 za = *reinterpret_cast<const float4*>(h2 + off);
    const float4 zb = *reinterpret_cast<const float4*>(x1 + off);
    Zs[c4 + 0][rr] = za.x + zb.x;
    Zs[c4 + 1][rr] = za.y + zb.y;
    Zs[c4 + 2][rr] = za.z + zb.z;
    Zs[c4 + 3][rr] = za.w + zb.w;
    float4 wv = make_float4(0.f, 0.f, 0.f, 0.f);
    if (wvalid) wv = *reinterpret_cast<const float4*>(wr + k0);
    Ws[c4 + 0][rr] = wv.x;
    Ws[c4 + 1][rr] = wv.y;
    Ws[c4 + 2][rr] = wv.z;
    Ws[c4 + 3][rr] = wv.w;
    __syncthreads();
#pragma unroll
    for (int kk = 0; kk < 16; ++kk) {
      const float4 av = *reinterpret_cast<const float4*>(&Zs[kk][ty * 4]);
      const float4 bv = *reinterpret_cast<const float4*>(&Ws[kk][tx * 4]);
      const float a_[4] = {av.x, av.y, av.z, av.w};
      const float b_[4] = {bv.x, bv.y, bv.z, bv.w};
#pragma unroll
      for (int i = 0; i < 4; ++i)
#pragma unroll
        for (int jj = 0; jj < 4; ++jj)
          acc[i][jj] = fmaf(a_[i], b_[jj], acc[i][jj]);
    }
    __syncthreads();
  }
#pragma unroll
  for (int i = 0; i < 4; ++i) {
    const int b = b0 + ty * 4 + i;
#pragma unroll
    for (int jj = 0; jj < 4; ++jj) {
      const int m = m0 + tx * 4 + jj;
      if (m < 1000) {
        const float vo = acc[i][jj] + b1[m];
        y1[(size_t)b * 1000 + m] = vo > 0.f ? vo : 0.f;
      }
    }
  }
}

// fc2: out[b,p] = sum_m y1[b,m]*w2[p,m] + b2[p], p<48; FP32 store.
__global__ __launch_bounds__(64) void fc2_kernel(
    const float* __restrict__ y1, const float* __restrict__ w2,
    const float* __restrict__ b2, float* __restrict__ out) {
  __shared__ float ys[1000];
  const int b = blockIdx.x;
  for (int k = threadIdx.x; k < 1000; k += 64) ys[k] = y1[(size_t)b * 1000 + k];
  __syncthreads();
  const int p = threadIdx.x;
  if (p < 48) {
    float a0 = b2[p], a1 = 0.f, a2 = 0.f, a3 = 0.f;
    const float* wr = w2 + (size_t)p * 1000;
    for (int k = 0; k < 1000; k += 4) {
      const float4 wv = *reinterpret_cast<const float4*>(wr + k);
      a0 = fmaf(ys[k + 0], wv.x, a0);
      a1 = fmaf(ys[k + 1], wv.y, a1);
      a2 = fmaf(ys[k + 2], wv.z, a2);
      a3 = fmaf(ys[k + 3], wv.w, a3);
    }
    out[(size_t)b * 48 + p] = (a0 + a1) + (a2 + a3);
  }
}

extern "C" void kernel_launch(void* const* d_in, const int* in_sizes, int n_in,
                              void* d_out, int out_size, void* d_ws,
                              size_t ws_size, hipStream_t stream) {
  const float* x = (const float*)d_in[0];
  const float* W_ih0_1 = (const float*)d_in[1];
  const float* W_ih_1 = (const float*)d_in[2];
  const float* W_hh_1 = (const float*)d_in[3];
  const float* b_ih_1 = (const float*)d_in[4];
  const float* b_hh_1 = (const float*)d_in[5];
  const float* W_ih_2 = (const float*)d_in[6];
  const float* W_hh_2 = (const float*)d_in[7];
  const float* b_ih_2 = (const float*)d_in[8];
  const float* b_hh_2 = (const float*)d_in[9];
  const float* fc1_w = (const float*)d_in[10];
  const float* fc1_b = (const float*)d_in[11];
  const float* fc2_w = (const float*)d_in[12];
  const float* fc2_b = (const float*)d_in[13];

  float* ws = (float*)d_ws;
  int* flags = (int*)d_ws;                 // 192 ints (256-float slot)
  float* hbuf = ws + 256;                  // 2*2*96*256*16 = 1,572,864
  float* x1b = hbuf + 1572864;             // 2*48*256*16  =   393,216
  float* h2b = x1b + 393216;               // 2*48*256*16  =   393,216
  float* y1 = h2b + 393216;                // 256,000
  // total ~10.5 MB

  hipMemsetAsync(flags, 0, 1024, stream);
  lstm_fused<<<192, 256, 0, stream>>>(x, W_ih0_1, W_ih_1, W_hh_1, b_ih_1,
                                      b_hh_1, W_ih_2, W_hh_2, b_ih_2, b_hh_2,
                                      hbuf, x1b, h2b, flags);
  fc1_kernel<<<dim3(16, 4), 256, 0, stream>>>(h2b, x1b, fc1_w, fc1_b, y1);
  fc2_kernel<<<256, 64, 0, stream>>>(y1, fc2_w, fc2_b, (float*)d_out);
}

// Round 7
// 2633.239 us; speedup vs baseline: 1.0981x; 1.0981x over previous
//
#include <hip/hip_runtime.h>

// ---------------------------------------------------------------------------
// Model: x:(256,1,96) -> 24-layer biLSTM (scan over batch axis: N=96 rows are
// independent chains, T=256 steps) -> slice n in [48,96) -> 24-layer biLSTM
// (N=48) -> z=h2+x1 -> fc1(1536->1000,relu) -> fc2(1000->48) -> FP32 out.
//
// Round-7: round-6's cross-block partner exchange (agent-scope release/
// acquire) forced per-XCD L2 writeback+invalidate every layer -> 110 MB HBM
// writes, 57 MB fetches, 2.75 ms. Fix: BOTH directions of a chain in ONE
// block. LDS = xgF[256*64] + xgB[256*64] = 128 KB (gfx950: 160 KB/WG max).
// Per layer: 4 waves compute fwd+bwd gates (input h in xgF cols 32..47 /
// xgB cols 48..63; per-row read-before-write within the owning wave), then
// wave 0 scans fwd on xgF CONCURRENTLY with wave 1 scanning bwd on xgB.
// Two __syncthreads per layer; no fences, no flags, no inter-block edges.
// 96 blocks (1/CU), one kernel for all 48 layer-stages.
// ---------------------------------------------------------------------------

template <int SEL>
__device__ __forceinline__ float quad_bcast(float v) {
  return __int_as_float(__builtin_amdgcn_update_dpp(
      0, __float_as_int(v), SEL * 0x55, 0xF, 0xF, true));
}

// x1g/h2g: (256,1536) row-major, k = n2*32 + d*16 + j  (n2 = n-48)
__global__ __launch_bounds__(256) void lstm_chain(
    const float* __restrict__ x, const float* __restrict__ W_ih0_1,
    const float* __restrict__ W_ih_1, const float* __restrict__ W_hh_1,
    const float* __restrict__ b_ih_1, const float* __restrict__ b_hh_1,
    const float* __restrict__ W_ih_2, const float* __restrict__ W_hh_2,
    const float* __restrict__ b_ih_2, const float* __restrict__ b_hh_2,
    float* __restrict__ x1g, float* __restrict__ h2g) {
  __shared__ float xgF[256 * 64];  // fwd gates; h_F lives in cols 32..47
  __shared__ float xgB[256 * 64];  // bwd gates; h_B lives in cols 48..63

  const int tid = threadIdx.x;
  const int lane = tid & 63;
  const int w = tid >> 6;
  const int n = blockIdx.x;
  const int nlay = (n < 48) ? 24 : 48;

  for (int L = 0; L < nlay; ++L) {
    const bool s2 = (L >= 24);
    const int l = s2 ? (L - 24) : L;
    const float* bih = s2 ? b_ih_2 : b_ih_1;
    const float* bhh = s2 ? b_hh_2 : b_hh_1;
    const float biasF = bih[l * 128 + lane] + bhh[l * 128 + lane];
    const float biasB = bih[l * 128 + 64 + lane] + bhh[l * 128 + 64 + lane];

    // ---- phase X: gate pre-activations for BOTH directions ----
    if (L == 0) {
      xgF[tid * 64 + 32] = x[(size_t)tid * 96 + n];  // stage x (in_sz=1)
      const float w0F = W_ih0_1[lane];
      const float w0B = W_ih0_1[64 + lane];
      __syncthreads();
      for (int ti = 0; ti < 64; ++ti) {
        const int t = w * 64 + ti;
        const float xs = xgF[t * 64 + 32];  // read precedes write (same wave)
        xgF[t * 64 + lane] = fmaf(w0F, xs, biasF);
        xgB[t * 64 + lane] = fmaf(w0B, xs, biasB);
      }
    } else {
      const float* Wih = s2 ? (W_ih_2 + (size_t)l * 4096)
                            : (W_ih_1 + (size_t)(l - 1) * 4096);
      float wf[32], wb[32];
      {
        const float4* wpF = reinterpret_cast<const float4*>(Wih + (size_t)lane * 32);
        const float4* wpB =
            reinterpret_cast<const float4*>(Wih + (size_t)(64 + lane) * 32);
#pragma unroll
        for (int q = 0; q < 8; ++q) {
          const float4 a = wpF[q];
          wf[4 * q + 0] = a.x; wf[4 * q + 1] = a.y;
          wf[4 * q + 2] = a.z; wf[4 * q + 3] = a.w;
          const float4 b = wpB[q];
          wb[4 * q + 0] = b.x; wb[4 * q + 1] = b.y;
          wb[4 * q + 2] = b.z; wb[4 * q + 3] = b.w;
        }
      }
      for (int ti = 0; ti < 64; ++ti) {
        const int t = w * 64 + ti;
        // input row: [hF (16) | hB (16)] from the two arrays (broadcast reads)
        const float4* hf4 = reinterpret_cast<const float4*>(&xgF[t * 64 + 32]);
        const float4* hb4 = reinterpret_cast<const float4*>(&xgB[t * 64 + 48]);
        float4 in[8];
#pragma unroll
        for (int q = 0; q < 4; ++q) in[q] = hf4[q];
#pragma unroll
        for (int q = 0; q < 4; ++q) in[4 + q] = hb4[q];
        float a0 = biasF, a1 = 0.f, a2 = 0.f, a3 = 0.f;
        float c0 = biasB, c1 = 0.f, c2 = 0.f, c3 = 0.f;
#pragma unroll
        for (int q = 0; q < 8; ++q) {
          const float4 v = in[q];
          a0 = fmaf(wf[4 * q + 0], v.x, a0);
          a1 = fmaf(wf[4 * q + 1], v.y, a1);
          a2 = fmaf(wf[4 * q + 2], v.z, a2);
          a3 = fmaf(wf[4 * q + 3], v.w, a3);
          c0 = fmaf(wb[4 * q + 0], v.x, c0);
          c1 = fmaf(wb[4 * q + 1], v.y, c1);
          c2 = fmaf(wb[4 * q + 2], v.z, c2);
          c3 = fmaf(wb[4 * q + 3], v.w, c3);
        }
        // reads of row t precede these writes (same wave, in-order DS)
        xgF[t * 64 + lane] = (a0 + a1) + (a2 + a3);
        xgB[t * 64 + lane] = (c0 + c1) + (c2 + c3);
      }
    }
    __syncthreads();

    // ---- scans: wave 0 = fwd on xgF, wave 1 = bwd on xgB (concurrent) ----
    if (w < 2) {
      float* xg = w ? xgB : xgF;
      const int d = w;
      const int jj = lane >> 2, g = lane & 3;
      const int r = g * 16 + jj;
      const int hcol = 32 + d * 16 + jj;  // fwd->xgF[32..47], bwd->xgB[48..63]
      const float* Whh =
          s2 ? (W_hh_2 + (size_t)l * 2048) : (W_hh_1 + (size_t)l * 2048);
      float whh[16];
#pragma unroll
      for (int k = 0; k < 16; ++k) whh[k] = Whh[((size_t)d * 64 + r) * 16 + k];
      const float s_ = (g == 2) ? 2.885390082f : -1.442695041f;
      const float m_ = (g == 2) ? -2.0f : 1.0f;
      const float b_ = (g == 2) ? 1.0f : 0.0f;
      float hs[16];
#pragma unroll
      for (int k = 0; k < 16; ++k) hs[k] = 0.f;
      float c = 0.f;
      const int dt = d ? -1 : 1;
      int t = d ? 255 : 0;
      float cur0 = xg[t * 64 + r];
      float cur1 = xg[(t + dt) * 64 + r];

#define LSTM_STEP(CUR, TT)                                                \
  {                                                                       \
    float a0 = (CUR), a1 = 0.f, a2 = 0.f, a3 = 0.f;                       \
    _Pragma("unroll") for (int k = 0; k < 16; k += 4) {                   \
      a0 = fmaf(whh[k + 0], hs[k + 0], a0);                               \
      a1 = fmaf(whh[k + 1], hs[k + 1], a1);                               \
      a2 = fmaf(whh[k + 2], hs[k + 2], a2);                               \
      a3 = fmaf(whh[k + 3], hs[k + 3], a3);                               \
    }                                                                     \
    const float gv = (a0 + a1) + (a2 + a3);                               \
    const float e = __builtin_amdgcn_exp2f(s_ * gv);                      \
    const float v = fmaf(m_, __builtin_amdgcn_rcpf(1.0f + e), b_);        \
    const float si = quad_bcast<0>(v);                                    \
    const float sf = quad_bcast<1>(v);                                    \
    const float tg = quad_bcast<2>(v);                                    \
    const float so = quad_bcast<3>(v);                                    \
    c = fmaf(sf, c, si * tg);                                             \
    const float e2 = __builtin_amdgcn_exp2f(2.885390082f * c);            \
    const float th = fmaf(-2.0f, __builtin_amdgcn_rcpf(1.0f + e2), 1.0f); \
    const float h = so * th;                                              \
    if (g == 0) xg[(TT)*64 + hcol] = h;                                   \
    const int hbb = __float_as_int(h);                                    \
    _Pragma("unroll") for (int k = 0; k < 16; ++k) hs[k] =                \
        __int_as_float(__builtin_amdgcn_readlane(hbb, 4 * k));            \
  }

      for (int tt = 0; tt < 256; tt += 2) {
        const float nx0 = xg[((t + 2 * dt) & 255) * 64 + r];
        LSTM_STEP(cur0, t)
        const float nx1 = xg[((t + 3 * dt) & 255) * 64 + r];
        LSTM_STEP(cur1, t + dt)
        cur0 = nx0;
        cur1 = nx1;
        t += 2 * dt;
      }
#undef LSTM_STEP
    }
    __syncthreads();

    // ---- write-out (block-uniform condition -> conditional sync is safe) --
    if ((L == 23 && n >= 48) || L == 47) {
      float* dst = (L == 23) ? x1g : h2g;
#pragma unroll
      for (int p = 0; p < 8; ++p) {
        const int idx = p * 256 + tid;
        const int t = idx >> 3, q = idx & 7;
        const float4 v =
            (q < 4) ? *reinterpret_cast<const float4*>(&xgF[t * 64 + 32 + q * 4])
                    : *reinterpret_cast<const float4*>(
                          &xgB[t * 64 + 48 + (q - 4) * 4]);
        *reinterpret_cast<float4*>(dst + (size_t)t * 1536 + (n - 48) * 32 +
                                   q * 4) = v;
      }
      __syncthreads();  // next layer's phase X overwrites the cols read above
    }
  }
}

// fc1: y1[b,m] = relu( sum_k (h2[b,k] + x1[b,k]) * w1[m,k] + b1[m] )
// 64x64 tiles, 256 threads, 4x4/thread; k-major LDS; register dbuf.
__global__ __launch_bounds__(256) void fc1_kernel(
    const float* __restrict__ h2,  // (256,1536)
    const float* __restrict__ x1,  // (256,1536)
    const float* __restrict__ w1, const float* __restrict__ b1,
    float* __restrict__ y1) {
  __shared__ float Zs[16][68];
  __shared__ float Ws[16][68];
  const int tid = threadIdx.x;
  const int m0 = blockIdx.x * 64;
  const int b0 = blockIdx.y * 64;
  const int rr = tid >> 2;
  const int c4 = (tid & 3) * 4;
  const int tx = tid & 15, ty = tid >> 4;

  float acc[4][4];
#pragma unroll
  for (int i = 0; i < 4; ++i)
#pragma unroll
    for (int jj = 0; jj < 4; ++jj) acc[i][jj] = 0.f;

  const bool wvalid = (m0 + rr) < 1000;
  const float* zr = h2 + (size_t)(b0 + rr) * 1536 + c4;
  const float* zr2 = x1 + (size_t)(b0 + rr) * 1536 + c4;
  const float* wr = w1 + (size_t)(m0 + rr) * 1536 + c4;

  float4 za = *reinterpret_cast<const float4*>(zr);
  float4 zb = *reinterpret_cast<const float4*>(zr2);
  float4 wv = wvalid ? *reinterpret_cast<const float4*>(wr)
                     : make_float4(0.f, 0.f, 0.f, 0.f);

  for (int k0 = 0; k0 < 1536; k0 += 16) {
    Zs[c4 + 0][rr] = za.x + zb.x;
    Zs[c4 + 1][rr] = za.y + zb.y;
    Zs[c4 + 2][rr] = za.z + zb.z;
    Zs[c4 + 3][rr] = za.w + zb.w;
    Ws[c4 + 0][rr] = wv.x;
    Ws[c4 + 1][rr] = wv.y;
    Ws[c4 + 2][rr] = wv.z;
    Ws[c4 + 3][rr] = wv.w;
    if (k0 + 16 < 1536) {
      za = *reinterpret_cast<const float4*>(zr + k0 + 16);
      zb = *reinterpret_cast<const float4*>(zr2 + k0 + 16);
      if (wvalid) wv = *reinterpret_cast<const float4*>(wr + k0 + 16);
    }
    __syncthreads();
#pragma unroll
    for (int kk = 0; kk < 16; ++kk) {
      const float4 av = *reinterpret_cast<const float4*>(&Zs[kk][ty * 4]);
      const float4 bv = *reinterpret_cast<const float4*>(&Ws[kk][tx * 4]);
      const float a_[4] = {av.x, av.y, av.z, av.w};
      const float b_[4] = {bv.x, bv.y, bv.z, bv.w};
#pragma unroll
      for (int i = 0; i < 4; ++i)
#pragma unroll
        for (int jj = 0; jj < 4; ++jj)
          acc[i][jj] = fmaf(a_[i], b_[jj], acc[i][jj]);
    }
    __syncthreads();
  }
#pragma unroll
  for (int i = 0; i < 4; ++i) {
    const int b = b0 + ty * 4 + i;
#pragma unroll
    for (int jj = 0; jj < 4; ++jj) {
      const int m = m0 + tx * 4 + jj;
      if (m < 1000) {
        const float vo = acc[i][jj] + b1[m];
        y1[(size_t)b * 1000 + m] = vo > 0.f ? vo : 0.f;
      }
    }
  }
}

// fc2: out[b,p] = sum_m y1[b,m]*w2[p,m] + b2[p], p<48; FP32 store.
__global__ __launch_bounds__(64) void fc2_kernel(
    const float* __restrict__ y1, const float* __restrict__ w2,
    const float* __restrict__ b2, float* __restrict__ out) {
  __shared__ float ys[1000];
  const int b = blockIdx.x;
  for (int k = threadIdx.x; k < 1000; k += 64) ys[k] = y1[(size_t)b * 1000 + k];
  __syncthreads();
  const int p = threadIdx.x;
  if (p < 48) {
    float a0 = b2[p], a1 = 0.f, a2 = 0.f, a3 = 0.f;
    const float* wr = w2 + (size_t)p * 1000;
    for (int k = 0; k < 1000; k += 4) {
      const float4 wv = *reinterpret_cast<const float4*>(wr + k);
      a0 = fmaf(ys[k + 0], wv.x, a0);
      a1 = fmaf(ys[k + 1], wv.y, a1);
      a2 = fmaf(ys[k + 2], wv.z, a2);
      a3 = fmaf(ys[k + 3], wv.w, a3);
    }
    out[(size_t)b * 48 + p] = (a0 + a1) + (a2 + a3);
  }
}

extern "C" void kernel_launch(void* const* d_in, const int* in_sizes, int n_in,
                              void* d_out, int out_size, void* d_ws,
                              size_t ws_size, hipStream_t stream) {
  const float* x = (const float*)d_in[0];
  const float* W_ih0_1 = (const float*)d_in[1];
  const float* W_ih_1 = (const float*)d_in[2];
  const float* W_hh_1 = (const float*)d_in[3];
  const float* b_ih_1 = (const float*)d_in[4];
  const float* b_hh_1 = (const float*)d_in[5];
  const float* W_ih_2 = (const float*)d_in[6];
  const float* W_hh_2 = (const float*)d_in[7];
  const float* b_ih_2 = (const float*)d_in[8];
  const float* b_hh_2 = (const float*)d_in[9];
  const float* fc1_w = (const float*)d_in[10];
  const float* fc1_b = (const float*)d_in[11];
  const float* fc2_w = (const float*)d_in[12];
  const float* fc2_b = (const float*)d_in[13];

  float* ws = (float*)d_ws;
  float* x1g = ws;             // 256*1536 = 393216
  float* h2g = ws + 393216;    // 393216
  float* y1 = ws + 786432;     // 256000

  lstm_chain<<<96, 256, 0, stream>>>(x, W_ih0_1, W_ih_1, W_hh_1, b_ih_1,
                                     b_hh_1, W_ih_2, W_hh_2, b_ih_2, b_hh_2,
                                     x1g, h2g);
  fc1_kernel<<<dim3(16, 4), 256, 0, stream>>>(h2g, x1g, fc1_w, fc1_b, y1);
  fc2_kernel<<<256, 64, 0, stream>>>(y1, fc2_w, fc2_b, (float*)d_out);
}